// Round 5
// baseline (210.273 us; speedup 1.0000x reference)
//
#include <hip/hip_runtime.h>
#include <hip/hip_cooperative_groups.h>

namespace cg = cooperative_groups;

// Problem constants (reference: B=32, L=64, C=4)
#define BB 32
#define LL 64
#define LC 256
#define NPAIR 2016
#define PPB 2                 // pairs per block
#define NBLK (NPAIR / PPB)    // 1008 blocks = ~4/CU (co-resident, coop-safe)
#define WSTR 1024             // ws partial stride per b (floats)

// v4 (resubmit x2; rounds 3-4 never acquired a GPU). Single cooperative
// dispatch. Evidence so far: the 256MiB ws poison fill (41us @6.5TB/s) is
// UNCONDITIONAL (persisted in v3 with ws unused), and our compute is
// arithmetically tiny (~1M L1-line transactions for the theta3 gather
// ~= 1.7us across 256 CUs). So the remaining controllable cost is dispatch
// count + kernel time. Structure:
//   phase 1: 1008 blocks x 2 pairs, coalesced float4 row gather,
//            per-(block,b) partial -> plain store into ws (poisoned anyway,
//            we overwrite before reading). 4 blocks/CU co-resident.
//   grid.sync()
//   phase 2: blocks 0..31 (one per b) reduce 1008 partials + theta1+theta0
//            -> single plain store to out. No atomics anywhere.
__global__ __launch_bounds__(256, 4) void fused_kernel(
    const float* __restrict__ x, const float* __restrict__ t0,
    const float* __restrict__ t1, const float* __restrict__ t2,
    const float* __restrict__ t3, float* __restrict__ ws,
    float* __restrict__ out)
{
    const int tid = threadIdx.x;
    const int j = blockIdx.x;
    __shared__ float wsum[4];

    // ---------------- phase 1: pair partials ----------------
    {
        const int b = tid >> 3, k = tid & 7;
        const float4* __restrict__ x4 = (const float4*)x + b * 64;

        // codes for my 8 w's (w = 8m+k): once per block, reused across pairs
        int c[8];
#pragma unroll
        for (int m = 0; m < 8; ++m) {
            float4 f = x4[8 * m + k];
            int ci = 0; float best = f.x;
            if (f.y > best) { best = f.y; ci = 1; }
            if (f.z > best) { best = f.z; ci = 2; }
            if (f.w > best) { best = f.w; ci = 3; }
            c[m] = ci;
        }

        // decode first pair index t = v*(v-1)/2 + u for this block
        const int tp0 = j * PPB;
        int v = (int)((1.0f + sqrtf(8.0f * (float)tp0 + 1.0f)) * 0.5f);
        while (v * (v - 1) / 2 > tp0) --v;
        while ((v + 1) * v / 2 <= tp0) ++v;
        int u = tp0 - v * (v - 1) / 2;

        float acc = 0.0f;
#pragma unroll
        for (int i = 0; i < PPB; ++i) {
            float4 fu = x4[u], fv = x4[v];   // block-uniform, L1 broadcast
            int cu = 0; { float bst = fu.x;
                if (fu.y > bst) { bst = fu.y; cu = 1; }
                if (fu.z > bst) { bst = fu.z; cu = 2; }
                if (fu.w > bst) { bst = fu.w; cu = 3; } }
            int cv = 0; { float bst = fv.x;
                if (fv.y > bst) { bst = fv.y; cv = 1; }
                if (fv.z > bst) { bst = fv.z; cv = 2; }
                if (fv.w > bst) { bst = fv.w; cv = 3; } }
            const int pu = 4 * u + cu, pv = 4 * v + cv;

            const float4* __restrict__ row4 =
                (const float4*)(t3 + ((size_t)pu << 16) + ((size_t)pv << 8));
            if (k == 0) acc += t2[pu * LC + pv];   // theta2 term

#pragma unroll
            for (int m = 0; m < 8; ++m) {
                const int w = 8 * m + k;
                float4 f = row4[w];                 // coalesced 16B, in-bounds
                const int ci = c[m];
                float lo = (ci & 1) ? f.y : f.x;    // cndmask chain
                float hi = (ci & 1) ? f.w : f.z;
                float val = (ci & 2) ? hi : lo;
                acc += (w > v) ? val : 0.0f;        // strict-triangle mask
            }

            ++u; if (u == v) { u = 0; ++v; }        // next pair
        }

        // width-8 shuffle reduce over k, store per-(block,b) partial
        acc += __shfl_down(acc, 4, 8);
        acc += __shfl_down(acc, 2, 8);
        acc += __shfl_down(acc, 1, 8);
        if (k == 0) ws[b * WSTR + j] = acc;
    }

    cg::this_grid().sync();

    // ---------------- phase 2: final reduce (blocks 0..31) ----------------
    if (j < BB) {
        const int b = j;
        const float* __restrict__ wsb = ws + b * WSTR;
        float s = 0.0f;
        for (int p = tid; p < NBLK; p += 256) s += wsb[p];   // coalesced
        if (tid < LL) {
            float4 f = ((const float4*)x)[b * 64 + tid];
            int c = 0; float best = f.x;
            if (f.y > best) { best = f.y; c = 1; }
            if (f.z > best) { best = f.z; c = 2; }
            if (f.w > best) { best = f.w; c = 3; }
            s += t1[4 * tid + c];
        }
        for (int off = 32; off > 0; off >>= 1) s += __shfl_down(s, off, 64);
        if ((tid & 63) == 0) wsum[tid >> 6] = s;
        __syncthreads();
        if (tid == 0) out[b] = wsum[0] + wsum[1] + wsum[2] + wsum[3] + t0[0];
    }
}

extern "C" void kernel_launch(void* const* d_in, const int* in_sizes, int n_in,
                              void* d_out, int out_size, void* d_ws, size_t ws_size,
                              hipStream_t stream) {
    const float* x  = (const float*)d_in[0];  // (B, L*C)
    const float* t0 = (const float*)d_in[1];  // (1,)
    const float* t1 = (const float*)d_in[2];  // (L, C)
    const float* t2 = (const float*)d_in[3];  // (L, C, L, C)
    const float* t3 = (const float*)d_in[4];  // (L, C, L, C, L, C)
    float* out = (float*)d_out;               // (B, 1)
    float* ws  = (float*)d_ws;                // uses 32*1024 floats = 128 KB

    void* args[] = { (void*)&x, (void*)&t0, (void*)&t1, (void*)&t2,
                     (void*)&t3, (void*)&ws, (void*)&out };
    hipLaunchCooperativeKernel((const void*)fused_kernel,
                               dim3(NBLK), dim3(256), args, 0, stream);
}